// Round 2
// baseline (1139.560 us; speedup 1.0000x reference)
//
#include <hip/hip_runtime.h>
#include <cstdint>
#include <cstddef>

typedef __bf16 bf16x8 __attribute__((ext_vector_type(8)));
typedef float  f32x4  __attribute__((ext_vector_type(4)));
typedef short  s16x8  __attribute__((ext_vector_type(8)));

static __device__ __forceinline__ float bf2f(short s) {
    union { unsigned u; float f; } v;
    v.u = ((unsigned)(unsigned short)s) << 16;
    return v.f;
}
static __device__ __forceinline__ short f2bf(float f) {
    unsigned u = __float_as_uint(f);
    u += 0x7fffu + ((u >> 16) & 1u);   // round-to-nearest-even
    return (short)(u >> 16);
}
static __device__ __forceinline__ float sigmoid_(float x) {
    return 1.0f / (1.0f + __expf(-x));
}
static __device__ __forceinline__ float tanh_(float x) {
    float ax = fabsf(x);
    float e  = __expf(-2.0f * ax);
    float t  = (1.0f - e) / (1.0f + e);
    return copysignf(t, x);
}

#define MFMA(a, b, c) __builtin_amdgcn_mfma_f32_16x16x32_bf16((a), (b), (c), 0, 0, 0)

// ---------------------------------------------------------------------------
// Kernel 0: transpose fp32 weights -> bf16 transposed copies in ws
// W1,W2: [128][128] fp32 -> [n][k] bf16; GK,GR: [128][384] fp32 -> [384][128] bf16
// ---------------------------------------------------------------------------
__global__ __launch_bounds__(256) void transpose_kernel(
    const float* __restrict__ W1, const float* __restrict__ W2,
    const float* __restrict__ GK, const float* __restrict__ GR,
    short* __restrict__ W1t, short* __restrict__ W2t,
    short* __restrict__ GKt, short* __restrict__ GRt)
{
    int i = blockIdx.x * 256 + threadIdx.x;
    if (i < 16384) {
        int k = i >> 7, n = i & 127;
        W1t[n * 128 + k] = f2bf(W1[i]);
        W2t[n * 128 + k] = f2bf(W2[i]);
    }
    if (i < 49152) {
        int k = i / 384, n = i - k * 384;
        GKt[n * 128 + k] = f2bf(GK[i]);
        GRt[n * 128 + k] = f2bf(GR[i]);
    }
}

static __device__ __forceinline__ s16x8 cvt8(const float* p) {
    f32x4 a0 = *(const f32x4*)(p);
    f32x4 a1 = *(const f32x4*)(p + 4);
    s16x8 v;
    v[0] = f2bf(a0[0]); v[1] = f2bf(a0[1]); v[2] = f2bf(a0[2]); v[3] = f2bf(a0[3]);
    v[4] = f2bf(a1[0]); v[5] = f2bf(a1[1]); v[6] = f2bf(a1[2]); v[7] = f2bf(a1[3]);
    return v;
}

// ---------------------------------------------------------------------------
// Kernel 1: msg = (X @ W1 + b1) @ W2 + b2   (bf16 MFMA, fused two GEMMs)
// Block: 256 thr (4 waves), 128-row tile. LDS: A-tile 32KB + W-tile 32KB.
// ---------------------------------------------------------------------------
__global__ __launch_bounds__(256) void msg_kernel(
    const float* __restrict__ X, const short* __restrict__ W1t,
    const float* __restrict__ b1, const short* __restrict__ W2t,
    const float* __restrict__ b2, short* __restrict__ msg, int N)
{
    __shared__ short ldsA[128 * 128];
    __shared__ short ldsW[128 * 128];
    const int tid  = threadIdx.x;
    const int m0   = blockIdx.x * 128;
    const int lane = tid & 63, wv = tid >> 6;
    const int q = lane >> 4, c = lane & 15;
    const int rowA0 = wv * 32;   // wave-private 32 rows

    // stage X tile (fp32 -> bf16) + W1^T (bf16)
    for (int i = tid; i < 128 * 16; i += 256) {
        int r = i >> 4, ch = (i & 15) * 8;
        s16x8 v;
        if (m0 + r < N) v = cvt8(X + (size_t)(m0 + r) * 128 + ch);
        else            v = (s16x8)0;
        *(s16x8*)(ldsA + r * 128 + ch) = v;
        *(s16x8*)(ldsW + r * 128 + ch) = *(const s16x8*)(W1t + r * 128 + ch);
    }
    __syncthreads();

    // ---- stage 1: Y1 = X @ W1 ----
    f32x4 acc[2][8];
#pragma unroll
    for (int t = 0; t < 2; t++)
#pragma unroll
        for (int n = 0; n < 8; n++) acc[t][n] = (f32x4)0.0f;

#pragma unroll
    for (int ks = 0; ks < 4; ks++) {
        int ko = ks * 32 + q * 8;
        bf16x8 a0 = __builtin_bit_cast(bf16x8, *(const s16x8*)(ldsA + (rowA0 + c) * 128 + ko));
        bf16x8 a1 = __builtin_bit_cast(bf16x8, *(const s16x8*)(ldsA + (rowA0 + 16 + c) * 128 + ko));
#pragma unroll
        for (int n = 0; n < 8; n++) {
            bf16x8 b = __builtin_bit_cast(bf16x8, *(const s16x8*)(ldsW + (n * 16 + c) * 128 + ko));
            acc[0][n] = MFMA(a0, b, acc[0][n]);
            acc[1][n] = MFMA(a1, b, acc[1][n]);
        }
    }

    // +b1, cvt bf16, write Y1 back into own rows of ldsA (same-wave ordering OK)
#pragma unroll
    for (int n = 0; n < 8; n++) {
        float bias = b1[n * 16 + c];
#pragma unroll
        for (int t = 0; t < 2; t++)
#pragma unroll
            for (int i = 0; i < 4; i++) {
                int row = rowA0 + t * 16 + q * 4 + i;
                ldsA[row * 128 + n * 16 + c] = f2bf(acc[t][n][i] + bias);
            }
    }
    __syncthreads();               // all waves done reading W1t
    // stage W2^T
    for (int i = tid; i < 128 * 16; i += 256) {
        int r = i >> 4, ch = (i & 15) * 8;
        *(s16x8*)(ldsW + r * 128 + ch) = *(const s16x8*)(W2t + r * 128 + ch);
    }
    __syncthreads();

    // ---- stage 2: msg = Y1 @ W2 ----
#pragma unroll
    for (int t = 0; t < 2; t++)
#pragma unroll
        for (int n = 0; n < 8; n++) acc[t][n] = (f32x4)0.0f;

#pragma unroll
    for (int ks = 0; ks < 4; ks++) {
        int ko = ks * 32 + q * 8;
        bf16x8 a0 = __builtin_bit_cast(bf16x8, *(const s16x8*)(ldsA + (rowA0 + c) * 128 + ko));
        bf16x8 a1 = __builtin_bit_cast(bf16x8, *(const s16x8*)(ldsA + (rowA0 + 16 + c) * 128 + ko));
#pragma unroll
        for (int n = 0; n < 8; n++) {
            bf16x8 b = __builtin_bit_cast(bf16x8, *(const s16x8*)(ldsW + (n * 16 + c) * 128 + ko));
            acc[0][n] = MFMA(a0, b, acc[0][n]);
            acc[1][n] = MFMA(a1, b, acc[1][n]);
        }
    }
#pragma unroll
    for (int n = 0; n < 8; n++) {
        float bias = b2[n * 16 + c];
#pragma unroll
        for (int t = 0; t < 2; t++)
#pragma unroll
            for (int i = 0; i < 4; i++) {
                int row = m0 + rowA0 + t * 16 + q * 4 + i;
                if (row < N) msg[(size_t)row * 128 + n * 16 + c] = f2bf(acc[t][n][i] + bias);
            }
    }
}

// ---------------------------------------------------------------------------
// Kernel 2: agg[b] += msg[a]; agg[a] += msg[b]  (fp32 atomics, wave per edge)
// msg is bf16 (2 elems per dword per lane).
// ---------------------------------------------------------------------------
__global__ __launch_bounds__(256) void scatter_kernel(
    const short* __restrict__ msg, const int* __restrict__ ra,
    const int* __restrict__ rb, float* __restrict__ agg, int E)
{
    const int lane = threadIdx.x & 63;
    int w = (int)((blockIdx.x * 256 + threadIdx.x) >> 6);
    const int nw = (gridDim.x * 256) >> 6;
    for (int e = w; e < E; e += nw) {
        int a = ra[e], b = rb[e];
        unsigned pa = *(const unsigned*)(msg + (size_t)a * 128 + lane * 2);
        unsigned pb = *(const unsigned*)(msg + (size_t)b * 128 + lane * 2);
        float ax = bf2f((short)(pa & 0xffff));
        float ay = bf2f((short)(pa >> 16));
        float bx = bf2f((short)(pb & 0xffff));
        float by = bf2f((short)(pb >> 16));
        float* outb = agg + (size_t)b * 128 + lane * 2;
        float* outa = agg + (size_t)a * 128 + lane * 2;
        unsafeAtomicAdd(outb,     ax);
        unsafeAtomicAdd(outb + 1, ay);
        unsafeAtomicAdd(outa,     bx);
        unsafeAtomicAdd(outa + 1, by);
    }
}

// ---------------------------------------------------------------------------
// Kernel 3: fused GRU.  mx = agg@GK + bias0, mh = X@GR + bias1, gates, out.
// Block: 256 thr, 128-row tile. Each wave owns col-tiles {wv, wv+4}, keeps all
// 24 B-fragments (z/r/h of GK^T and GR^T) in registers across the row loop.
// ---------------------------------------------------------------------------
__global__ __launch_bounds__(256) void gru_kernel(
    const float* __restrict__ agg, const float* __restrict__ X,
    const short* __restrict__ GKt, const short* __restrict__ GRt,
    const float* __restrict__ gbias, float* __restrict__ out, int N)
{
    __shared__ short ldsA[128 * 128];   // agg tile (bf16)
    __shared__ short ldsX[128 * 128];   // X tile (bf16)
    const int tid  = threadIdx.x;
    const int m0   = blockIdx.x * 128;
    const int lane = tid & 63, wv = tid >> 6;
    const int q = lane >> 4, c = lane & 15;

    for (int i = tid; i < 128 * 16; i += 256) {
        int r = i >> 4, ch = (i & 15) * 8;
        s16x8 vx, va;
        if (m0 + r < N) {
            vx = cvt8(X   + (size_t)(m0 + r) * 128 + ch);
            va = cvt8(agg + (size_t)(m0 + r) * 128 + ch);
        } else { vx = (s16x8)0; va = (s16x8)0; }
        *(s16x8*)(ldsX + r * 128 + ch) = vx;
        *(s16x8*)(ldsA + r * 128 + ch) = va;
    }
    __syncthreads();

#pragma clang loop unroll(disable)
    for (int nn = 0; nn < 2; nn++) {
        const int nt   = wv + nn * 4;       // output col-tile 0..7
        const int ncol = nt * 16 + c;

        // B-fragments: rows of GK^T/GR^T = gate columns {ncol, 128+ncol, 256+ncol}
        bf16x8 bkz[4], bkr[4], bkh[4], brz[4], brr[4], brh[4];
#pragma unroll
        for (int ks = 0; ks < 4; ks++) {
            int ko = ks * 32 + q * 8;
            bkz[ks] = __builtin_bit_cast(bf16x8, *(const s16x8*)(GKt + (size_t)(ncol)       * 128 + ko));
            bkr[ks] = __builtin_bit_cast(bf16x8, *(const s16x8*)(GKt + (size_t)(128 + ncol) * 128 + ko));
            bkh[ks] = __builtin_bit_cast(bf16x8, *(const s16x8*)(GKt + (size_t)(256 + ncol) * 128 + ko));
            brz[ks] = __builtin_bit_cast(bf16x8, *(const s16x8*)(GRt + (size_t)(ncol)       * 128 + ko));
            brr[ks] = __builtin_bit_cast(bf16x8, *(const s16x8*)(GRt + (size_t)(128 + ncol) * 128 + ko));
            brh[ks] = __builtin_bit_cast(bf16x8, *(const s16x8*)(GRt + (size_t)(256 + ncol) * 128 + ko));
        }
        float bz0 = gbias[ncol],       br0 = gbias[128 + ncol],       bh0 = gbias[256 + ncol];
        float bz1 = gbias[384 + ncol], br1 = gbias[384 + 128 + ncol], bh1 = gbias[384 + 256 + ncol];

#pragma clang loop unroll(disable)
        for (int rt = 0; rt < 8; rt++) {
            f32x4 axz = (f32x4)0.0f, axr = (f32x4)0.0f, axh = (f32x4)0.0f;
            f32x4 arz = (f32x4)0.0f, arr = (f32x4)0.0f, arh = (f32x4)0.0f;
#pragma unroll
            for (int ks = 0; ks < 4; ks++) {
                int ko = ks * 32 + q * 8;
                bf16x8 aA = __builtin_bit_cast(bf16x8, *(const s16x8*)(ldsA + (rt * 16 + c) * 128 + ko));
                bf16x8 aX = __builtin_bit_cast(bf16x8, *(const s16x8*)(ldsX + (rt * 16 + c) * 128 + ko));
                axz = MFMA(aA, bkz[ks], axz);
                axr = MFMA(aA, bkr[ks], axr);
                axh = MFMA(aA, bkh[ks], axh);
                arz = MFMA(aX, brz[ks], arz);
                arr = MFMA(aX, brr[ks], arr);
                arh = MFMA(aX, brh[ks], arh);
            }
#pragma unroll
            for (int i = 0; i < 4; i++) {
                int row  = rt * 16 + q * 4 + i;
                int grow = m0 + row;
                if (grow < N) {
                    float z  = sigmoid_(axz[i] + bz0 + arz[i] + bz1);
                    float r  = sigmoid_(axr[i] + br0 + arr[i] + br1);
                    float hh = tanh_(axh[i] + bh0 + r * (arh[i] + bh1));
                    float xv = X[(size_t)grow * 128 + ncol];   // fp32 for exact blend
                    out[(size_t)grow * 128 + ncol] = z * xv + (1.0f - z) * hh;
                }
            }
        }
    }
}

// ---------------------------------------------------------------------------
extern "C" void kernel_launch(void* const* d_in, const int* in_sizes, int n_in,
                              void* d_out, int out_size, void* d_ws, size_t ws_size,
                              hipStream_t stream)
{
    const float* X  = (const float*)d_in[0];
    const int*   ra = (const int*)d_in[1];
    const int*   rb = (const int*)d_in[2];
    const float* W1 = (const float*)d_in[3];
    const float* b1 = (const float*)d_in[4];
    const float* W2 = (const float*)d_in[5];
    const float* b2 = (const float*)d_in[6];
    const float* GK = (const float*)d_in[7];
    const float* GR = (const float*)d_in[8];
    const float* GB = (const float*)d_in[9];
    const int N = in_sizes[0] / 128;
    const int E = in_sizes[1];
    float* out = (float*)d_out;

    char* ws = (char*)d_ws;
    float* agg = (float*)ws;
    size_t off = (size_t)N * 128 * 4;
    short* msg = (short*)(ws + off); off += (size_t)N * 128 * 2;
    short* W1t = (short*)(ws + off); off += 16384u * 2;
    short* W2t = (short*)(ws + off); off += 16384u * 2;
    short* GKt = (short*)(ws + off); off += 49152u * 2;
    short* GRt = (short*)(ws + off); off += 49152u * 2;

    hipMemsetAsync(agg, 0, (size_t)N * 128 * 4, stream);
    transpose_kernel<<<192, 256, 0, stream>>>(W1, W2, GK, GR, W1t, W2t, GKt, GRt);

    const int nblk = (N + 127) / 128;
    msg_kernel<<<nblk, 256, 0, stream>>>(X, W1t, b1, W2t, b2, msg, N);
    scatter_kernel<<<2048, 256, 0, stream>>>(msg, ra, rb, agg, E);
    gru_kernel<<<nblk, 256, 0, stream>>>(agg, X, GKt, GRt, GB, out, N);
}

// Round 3
// 427.472 us; speedup vs baseline: 2.6658x; 2.6658x over previous
//
#include <hip/hip_runtime.h>
#include <cstdint>
#include <cstddef>

typedef __bf16 bf16x8 __attribute__((ext_vector_type(8)));
typedef float  f32x4  __attribute__((ext_vector_type(4)));
typedef short  s16x8  __attribute__((ext_vector_type(8)));

static __device__ __forceinline__ float bf2f(short s) {
    union { unsigned u; float f; } v;
    v.u = ((unsigned)(unsigned short)s) << 16;
    return v.f;
}
static __device__ __forceinline__ short f2bf(float f) {
    unsigned u = __float_as_uint(f);
    u += 0x7fffu + ((u >> 16) & 1u);   // round-to-nearest-even
    return (short)(u >> 16);
}
static __device__ __forceinline__ float sigmoid_(float x) {
    return 1.0f / (1.0f + __expf(-x));
}
static __device__ __forceinline__ float tanh_(float x) {
    float ax = fabsf(x);
    float e  = __expf(-2.0f * ax);
    float t  = (1.0f - e) / (1.0f + e);
    return copysignf(t, x);
}

#define MFMA(a, b, c) __builtin_amdgcn_mfma_f32_16x16x32_bf16((a), (b), (c), 0, 0, 0)

// ---------------------------------------------------------------------------
// Kernel 0: transpose fp32 weights -> bf16 transposed copies in ws
// ---------------------------------------------------------------------------
__global__ __launch_bounds__(256) void transpose_kernel(
    const float* __restrict__ W1, const float* __restrict__ W2,
    const float* __restrict__ GK, const float* __restrict__ GR,
    short* __restrict__ W1t, short* __restrict__ W2t,
    short* __restrict__ GKt, short* __restrict__ GRt)
{
    int i = blockIdx.x * 256 + threadIdx.x;
    if (i < 16384) {
        int k = i >> 7, n = i & 127;
        W1t[n * 128 + k] = f2bf(W1[i]);
        W2t[n * 128 + k] = f2bf(W2[i]);
    }
    if (i < 49152) {
        int k = i / 384, n = i - k * 384;
        GKt[n * 128 + k] = f2bf(GK[i]);
        GRt[n * 128 + k] = f2bf(GR[i]);
    }
}

static __device__ __forceinline__ s16x8 cvt8(const float* p) {
    f32x4 a0 = *(const f32x4*)(p);
    f32x4 a1 = *(const f32x4*)(p + 4);
    s16x8 v;
    v[0] = f2bf(a0[0]); v[1] = f2bf(a0[1]); v[2] = f2bf(a0[2]); v[3] = f2bf(a0[3]);
    v[4] = f2bf(a1[0]); v[5] = f2bf(a1[1]); v[6] = f2bf(a1[2]); v[7] = f2bf(a1[3]);
    return v;
}

// ---------------------------------------------------------------------------
// Kernel 1: msg = (X @ W1 + b1) @ W2 + b2   (bf16 MFMA, fused two GEMMs)
// ---------------------------------------------------------------------------
__global__ __launch_bounds__(256) void msg_kernel(
    const float* __restrict__ X, const short* __restrict__ W1t,
    const float* __restrict__ b1, const short* __restrict__ W2t,
    const float* __restrict__ b2, short* __restrict__ msg, int N)
{
    __shared__ short ldsA[128 * 128];
    __shared__ short ldsW[128 * 128];
    const int tid  = threadIdx.x;
    const int m0   = blockIdx.x * 128;
    const int lane = tid & 63, wv = tid >> 6;
    const int q = lane >> 4, c = lane & 15;
    const int rowA0 = wv * 32;   // wave-private 32 rows

    for (int i = tid; i < 128 * 16; i += 256) {
        int r = i >> 4, ch = (i & 15) * 8;
        s16x8 v;
        if (m0 + r < N) v = cvt8(X + (size_t)(m0 + r) * 128 + ch);
        else            v = (s16x8)0;
        *(s16x8*)(ldsA + r * 128 + ch) = v;
        *(s16x8*)(ldsW + r * 128 + ch) = *(const s16x8*)(W1t + r * 128 + ch);
    }
    __syncthreads();

    f32x4 acc[2][8];
#pragma unroll
    for (int t = 0; t < 2; t++)
#pragma unroll
        for (int n = 0; n < 8; n++) acc[t][n] = (f32x4)0.0f;

#pragma unroll
    for (int ks = 0; ks < 4; ks++) {
        int ko = ks * 32 + q * 8;
        bf16x8 a0 = __builtin_bit_cast(bf16x8, *(const s16x8*)(ldsA + (rowA0 + c) * 128 + ko));
        bf16x8 a1 = __builtin_bit_cast(bf16x8, *(const s16x8*)(ldsA + (rowA0 + 16 + c) * 128 + ko));
#pragma unroll
        for (int n = 0; n < 8; n++) {
            bf16x8 b = __builtin_bit_cast(bf16x8, *(const s16x8*)(ldsW + (n * 16 + c) * 128 + ko));
            acc[0][n] = MFMA(a0, b, acc[0][n]);
            acc[1][n] = MFMA(a1, b, acc[1][n]);
        }
    }

#pragma unroll
    for (int n = 0; n < 8; n++) {
        float bias = b1[n * 16 + c];
#pragma unroll
        for (int t = 0; t < 2; t++)
#pragma unroll
            for (int i = 0; i < 4; i++) {
                int row = rowA0 + t * 16 + q * 4 + i;
                ldsA[row * 128 + n * 16 + c] = f2bf(acc[t][n][i] + bias);
            }
    }
    __syncthreads();
    for (int i = tid; i < 128 * 16; i += 256) {
        int r = i >> 4, ch = (i & 15) * 8;
        *(s16x8*)(ldsW + r * 128 + ch) = *(const s16x8*)(W2t + r * 128 + ch);
    }
    __syncthreads();

#pragma unroll
    for (int t = 0; t < 2; t++)
#pragma unroll
        for (int n = 0; n < 8; n++) acc[t][n] = (f32x4)0.0f;

#pragma unroll
    for (int ks = 0; ks < 4; ks++) {
        int ko = ks * 32 + q * 8;
        bf16x8 a0 = __builtin_bit_cast(bf16x8, *(const s16x8*)(ldsA + (rowA0 + c) * 128 + ko));
        bf16x8 a1 = __builtin_bit_cast(bf16x8, *(const s16x8*)(ldsA + (rowA0 + 16 + c) * 128 + ko));
#pragma unroll
        for (int n = 0; n < 8; n++) {
            bf16x8 b = __builtin_bit_cast(bf16x8, *(const s16x8*)(ldsW + (n * 16 + c) * 128 + ko));
            acc[0][n] = MFMA(a0, b, acc[0][n]);
            acc[1][n] = MFMA(a1, b, acc[1][n]);
        }
    }
#pragma unroll
    for (int n = 0; n < 8; n++) {
        float bias = b2[n * 16 + c];
#pragma unroll
        for (int t = 0; t < 2; t++)
#pragma unroll
            for (int i = 0; i < 4; i++) {
                int row = m0 + rowA0 + t * 16 + q * 4 + i;
                if (row < N) msg[(size_t)row * 128 + n * 16 + c] = f2bf(acc[t][n][i] + bias);
            }
    }
}

// ---------------------------------------------------------------------------
// CSR build: histogram -> slab starts (unordered) -> fill
// ---------------------------------------------------------------------------
__global__ __launch_bounds__(256) void count_kernel(
    const int* __restrict__ ra, const int* __restrict__ rb,
    int* __restrict__ counts, int E)
{
    int e = blockIdx.x * 256 + threadIdx.x;
    if (e < E) {
        atomicAdd(&counts[rb[e]], 1);
        atomicAdd(&counts[ra[e]], 1);
    }
}

__global__ __launch_bounds__(256) void starts_kernel(
    const int* __restrict__ counts, int* __restrict__ starts,
    int* __restrict__ cur, int* __restrict__ cursor, int N)
{
    int i = blockIdx.x * 256 + threadIdx.x;
    int lane = threadIdx.x & 63;
    int c = (i < N) ? counts[i] : 0;
    int v = c;
#pragma unroll
    for (int d = 1; d < 64; d <<= 1) {
        int t = __shfl_up(v, d);
        if (lane >= d) v += t;
    }
    int total = __shfl(v, 63);
    int base = 0;
    if (lane == 0) base = atomicAdd(cursor, total);
    base = __shfl(base, 0);
    if (i < N) {
        int s = base + v - c;
        starts[i] = s;
        cur[i] = s;
    }
}

__global__ __launch_bounds__(256) void fill_kernel(
    const int* __restrict__ ra, const int* __restrict__ rb,
    int* __restrict__ cur, int* __restrict__ nbr, int E)
{
    int e = blockIdx.x * 256 + threadIdx.x;
    if (e < E) {
        int a = ra[e], b = rb[e];
        int p = atomicAdd(&cur[b], 1); nbr[p] = a;
        int q = atomicAdd(&cur[a], 1); nbr[q] = b;
    }
}

// ---------------------------------------------------------------------------
// Kernel 2: gather — one wave per node, agg[i] = sum_{j in adj(i)} msg[j]
// fp32 register accumulation, bf16 output (GRU consumed bf16 anyway).
// ---------------------------------------------------------------------------
__global__ __launch_bounds__(256) void gather_kernel(
    const short* __restrict__ msg, const int* __restrict__ starts,
    const int* __restrict__ counts, const int* __restrict__ nbr,
    short* __restrict__ aggb, int N)
{
    const int lane = threadIdx.x & 63;
    const int node = blockIdx.x * 4 + (threadIdx.x >> 6);
    if (node >= N) return;
    const int s = starts[node], cnt = counts[node];
    float a0 = 0.0f, a1 = 0.0f;
    for (int n = s; n < s + cnt; n++) {
        int j = nbr[n];
        unsigned p = *(const unsigned*)(msg + (size_t)j * 128 + lane * 2);
        a0 += bf2f((short)(p & 0xffff));
        a1 += bf2f((short)(p >> 16));
    }
    unsigned o = ((unsigned)(unsigned short)f2bf(a1) << 16) |
                  (unsigned)(unsigned short)f2bf(a0);
    *(unsigned*)(aggb + (size_t)node * 128 + lane * 2) = o;
}

// ---------------------------------------------------------------------------
// Kernel 3: fused GRU (agg now bf16).
// ---------------------------------------------------------------------------
__global__ __launch_bounds__(256) void gru_kernel(
    const short* __restrict__ aggb, const float* __restrict__ X,
    const short* __restrict__ GKt, const short* __restrict__ GRt,
    const float* __restrict__ gbias, float* __restrict__ out, int N)
{
    __shared__ short ldsA[128 * 128];   // agg tile (bf16)
    __shared__ short ldsX[128 * 128];   // X tile (bf16)
    const int tid  = threadIdx.x;
    const int m0   = blockIdx.x * 128;
    const int lane = tid & 63, wv = tid >> 6;
    const int q = lane >> 4, c = lane & 15;

    for (int i = tid; i < 128 * 16; i += 256) {
        int r = i >> 4, ch = (i & 15) * 8;
        s16x8 vx, va;
        if (m0 + r < N) {
            vx = cvt8(X + (size_t)(m0 + r) * 128 + ch);
            va = *(const s16x8*)(aggb + (size_t)(m0 + r) * 128 + ch);
        } else { vx = (s16x8)0; va = (s16x8)0; }
        *(s16x8*)(ldsX + r * 128 + ch) = vx;
        *(s16x8*)(ldsA + r * 128 + ch) = va;
    }
    __syncthreads();

#pragma clang loop unroll(disable)
    for (int nn = 0; nn < 2; nn++) {
        const int nt   = wv + nn * 4;
        const int ncol = nt * 16 + c;

        bf16x8 bkz[4], bkr[4], bkh[4], brz[4], brr[4], brh[4];
#pragma unroll
        for (int ks = 0; ks < 4; ks++) {
            int ko = ks * 32 + q * 8;
            bkz[ks] = __builtin_bit_cast(bf16x8, *(const s16x8*)(GKt + (size_t)(ncol)       * 128 + ko));
            bkr[ks] = __builtin_bit_cast(bf16x8, *(const s16x8*)(GKt + (size_t)(128 + ncol) * 128 + ko));
            bkh[ks] = __builtin_bit_cast(bf16x8, *(const s16x8*)(GKt + (size_t)(256 + ncol) * 128 + ko));
            brz[ks] = __builtin_bit_cast(bf16x8, *(const s16x8*)(GRt + (size_t)(ncol)       * 128 + ko));
            brr[ks] = __builtin_bit_cast(bf16x8, *(const s16x8*)(GRt + (size_t)(128 + ncol) * 128 + ko));
            brh[ks] = __builtin_bit_cast(bf16x8, *(const s16x8*)(GRt + (size_t)(256 + ncol) * 128 + ko));
        }
        float bz0 = gbias[ncol],       br0 = gbias[128 + ncol],       bh0 = gbias[256 + ncol];
        float bz1 = gbias[384 + ncol], br1 = gbias[384 + 128 + ncol], bh1 = gbias[384 + 256 + ncol];

#pragma clang loop unroll(disable)
        for (int rt = 0; rt < 8; rt++) {
            f32x4 axz = (f32x4)0.0f, axr = (f32x4)0.0f, axh = (f32x4)0.0f;
            f32x4 arz = (f32x4)0.0f, arr = (f32x4)0.0f, arh = (f32x4)0.0f;
#pragma unroll
            for (int ks = 0; ks < 4; ks++) {
                int ko = ks * 32 + q * 8;
                bf16x8 aA = __builtin_bit_cast(bf16x8, *(const s16x8*)(ldsA + (rt * 16 + c) * 128 + ko));
                bf16x8 aX = __builtin_bit_cast(bf16x8, *(const s16x8*)(ldsX + (rt * 16 + c) * 128 + ko));
                axz = MFMA(aA, bkz[ks], axz);
                axr = MFMA(aA, bkr[ks], axr);
                axh = MFMA(aA, bkh[ks], axh);
                arz = MFMA(aX, brz[ks], arz);
                arr = MFMA(aX, brr[ks], arr);
                arh = MFMA(aX, brh[ks], arh);
            }
#pragma unroll
            for (int i = 0; i < 4; i++) {
                int row  = rt * 16 + q * 4 + i;
                int grow = m0 + row;
                if (grow < N) {
                    float z  = sigmoid_(axz[i] + bz0 + arz[i] + bz1);
                    float r  = sigmoid_(axr[i] + br0 + arr[i] + br1);
                    float hh = tanh_(axh[i] + bh0 + r * (arh[i] + bh1));
                    float xv = X[(size_t)grow * 128 + ncol];   // fp32 for exact blend
                    out[(size_t)grow * 128 + ncol] = z * xv + (1.0f - z) * hh;
                }
            }
        }
    }
}

// ---------------------------------------------------------------------------
extern "C" void kernel_launch(void* const* d_in, const int* in_sizes, int n_in,
                              void* d_out, int out_size, void* d_ws, size_t ws_size,
                              hipStream_t stream)
{
    const float* X  = (const float*)d_in[0];
    const int*   ra = (const int*)d_in[1];
    const int*   rb = (const int*)d_in[2];
    const float* W1 = (const float*)d_in[3];
    const float* b1 = (const float*)d_in[4];
    const float* W2 = (const float*)d_in[5];
    const float* b2 = (const float*)d_in[6];
    const float* GK = (const float*)d_in[7];
    const float* GR = (const float*)d_in[8];
    const float* GB = (const float*)d_in[9];
    const int N = in_sizes[0] / 128;
    const int E = in_sizes[1];
    float* out = (float*)d_out;

    char* ws = (char*)d_ws;
    size_t off = 0;
    short* aggb = (short*)(ws + off); off += (size_t)N * 128 * 2;   // bf16 agg
    short* msg  = (short*)(ws + off); off += (size_t)N * 128 * 2;
    short* W1t  = (short*)(ws + off); off += 16384u * 2;
    short* W2t  = (short*)(ws + off); off += 16384u * 2;
    short* GKt  = (short*)(ws + off); off += 49152u * 2;
    short* GRt  = (short*)(ws + off); off += 49152u * 2;
    int* counts = (int*)(ws + off);   off += (size_t)N * 4;
    int* cursor = (int*)(ws + off);   off += 4;
    int* starts = (int*)(ws + off);   off += (size_t)N * 4;
    int* cur    = (int*)(ws + off);   off += (size_t)N * 4;
    int* nbr    = (int*)(ws + off);   off += (size_t)2 * E * 4;

    // zero counts + cursor (contiguous)
    hipMemsetAsync(counts, 0, ((size_t)N + 1) * 4, stream);
    transpose_kernel<<<192, 256, 0, stream>>>(W1, W2, GK, GR, W1t, W2t, GKt, GRt);

    const int eblk = (E + 255) / 256;
    count_kernel<<<eblk, 256, 0, stream>>>(ra, rb, counts, E);
    starts_kernel<<<(N + 255) / 256, 256, 0, stream>>>(counts, starts, cur, cursor, N);
    fill_kernel<<<eblk, 256, 0, stream>>>(ra, rb, cur, nbr, E);

    const int nblk = (N + 127) / 128;
    msg_kernel<<<nblk, 256, 0, stream>>>(X, W1t, b1, W2t, b2, msg, N);
    gather_kernel<<<(N + 3) / 4, 256, 0, stream>>>(msg, starts, counts, nbr, aggb, N);
    gru_kernel<<<nblk, 256, 0, stream>>>(aggb, X, GKt, GRt, GB, out, N);
}

// Round 4
// 359.226 us; speedup vs baseline: 3.1723x; 1.1900x over previous
//
#include <hip/hip_runtime.h>
#include <cstdint>
#include <cstddef>

typedef __bf16 bf16x8 __attribute__((ext_vector_type(8)));
typedef float  f32x4  __attribute__((ext_vector_type(4)));
typedef short  s16x8  __attribute__((ext_vector_type(8)));

static __device__ __forceinline__ float bf2f(short s) {
    union { unsigned u; float f; } v;
    v.u = ((unsigned)(unsigned short)s) << 16;
    return v.f;
}
static __device__ __forceinline__ short f2bf(float f) {
    unsigned u = __float_as_uint(f);
    u += 0x7fffu + ((u >> 16) & 1u);   // round-to-nearest-even
    return (short)(u >> 16);
}
static __device__ __forceinline__ float sigmoid_(float x) {
    return 1.0f / (1.0f + __expf(-x));
}
static __device__ __forceinline__ float tanh_(float x) {
    float ax = fabsf(x);
    float e  = __expf(-2.0f * ax);
    float t  = (1.0f - e) / (1.0f + e);
    return copysignf(t, x);
}

#define MFMA(a, b, c) __builtin_amdgcn_mfma_f32_16x16x32_bf16((a), (b), (c), 0, 0, 0)

// ---------------------------------------------------------------------------
// Kernel 0: prep — transpose fp32 weights -> bf16 transposed copies in ws,
// zero counts + cursor (replaces hipMemsetAsync + transpose: one dispatch).
// ---------------------------------------------------------------------------
__global__ __launch_bounds__(256) void prep_kernel(
    const float* __restrict__ W1, const float* __restrict__ W2,
    const float* __restrict__ GK, const float* __restrict__ GR,
    short* __restrict__ W1t, short* __restrict__ W2t,
    short* __restrict__ GKt, short* __restrict__ GRt,
    int* __restrict__ counts, int* __restrict__ cursor, int N)
{
    int i = blockIdx.x * 256 + threadIdx.x;
    if (i < 16384) {
        int k = i >> 7, n = i & 127;
        W1t[n * 128 + k] = f2bf(W1[i]);
        W2t[n * 128 + k] = f2bf(W2[i]);
    }
    if (i < 49152) {
        int k = i / 384, n = i - k * 384;
        GKt[n * 128 + k] = f2bf(GK[i]);
        GRt[n * 128 + k] = f2bf(GR[i]);
    }
    if (i < N) counts[i] = 0;
    if (i == 0) *cursor = 0;
}

static __device__ __forceinline__ s16x8 cvt8(const float* p) {
    f32x4 a0 = *(const f32x4*)(p);
    f32x4 a1 = *(const f32x4*)(p + 4);
    s16x8 v;
    v[0] = f2bf(a0[0]); v[1] = f2bf(a0[1]); v[2] = f2bf(a0[2]); v[3] = f2bf(a0[3]);
    v[4] = f2bf(a1[0]); v[5] = f2bf(a1[1]); v[6] = f2bf(a1[2]); v[7] = f2bf(a1[3]);
    return v;
}

// ---------------------------------------------------------------------------
// Kernel 1: msg = (X @ W1 + b1) @ W2 + b2   (bf16 MFMA, fused two GEMMs)
// ---------------------------------------------------------------------------
__global__ __launch_bounds__(256) void msg_kernel(
    const float* __restrict__ X, const short* __restrict__ W1t,
    const float* __restrict__ b1, const short* __restrict__ W2t,
    const float* __restrict__ b2, short* __restrict__ msg, int N)
{
    __shared__ short ldsA[128 * 128];
    __shared__ short ldsW[128 * 128];
    const int tid  = threadIdx.x;
    const int m0   = blockIdx.x * 128;
    const int lane = tid & 63, wv = tid >> 6;
    const int q = lane >> 4, c = lane & 15;
    const int rowA0 = wv * 32;   // wave-private 32 rows

    for (int i = tid; i < 128 * 16; i += 256) {
        int r = i >> 4, ch = (i & 15) * 8;
        s16x8 v;
        if (m0 + r < N) v = cvt8(X + (size_t)(m0 + r) * 128 + ch);
        else            v = (s16x8)0;
        *(s16x8*)(ldsA + r * 128 + ch) = v;
        *(s16x8*)(ldsW + r * 128 + ch) = *(const s16x8*)(W1t + r * 128 + ch);
    }
    __syncthreads();

    f32x4 acc[2][8];
#pragma unroll
    for (int t = 0; t < 2; t++)
#pragma unroll
        for (int n = 0; n < 8; n++) acc[t][n] = (f32x4)0.0f;

#pragma unroll
    for (int ks = 0; ks < 4; ks++) {
        int ko = ks * 32 + q * 8;
        bf16x8 a0 = __builtin_bit_cast(bf16x8, *(const s16x8*)(ldsA + (rowA0 + c) * 128 + ko));
        bf16x8 a1 = __builtin_bit_cast(bf16x8, *(const s16x8*)(ldsA + (rowA0 + 16 + c) * 128 + ko));
#pragma unroll
        for (int n = 0; n < 8; n++) {
            bf16x8 b = __builtin_bit_cast(bf16x8, *(const s16x8*)(ldsW + (n * 16 + c) * 128 + ko));
            acc[0][n] = MFMA(a0, b, acc[0][n]);
            acc[1][n] = MFMA(a1, b, acc[1][n]);
        }
    }

#pragma unroll
    for (int n = 0; n < 8; n++) {
        float bias = b1[n * 16 + c];
#pragma unroll
        for (int t = 0; t < 2; t++)
#pragma unroll
            for (int i = 0; i < 4; i++) {
                int row = rowA0 + t * 16 + q * 4 + i;
                ldsA[row * 128 + n * 16 + c] = f2bf(acc[t][n][i] + bias);
            }
    }
    __syncthreads();
    for (int i = tid; i < 128 * 16; i += 256) {
        int r = i >> 4, ch = (i & 15) * 8;
        *(s16x8*)(ldsW + r * 128 + ch) = *(const s16x8*)(W2t + r * 128 + ch);
    }
    __syncthreads();

#pragma unroll
    for (int t = 0; t < 2; t++)
#pragma unroll
        for (int n = 0; n < 8; n++) acc[t][n] = (f32x4)0.0f;

#pragma unroll
    for (int ks = 0; ks < 4; ks++) {
        int ko = ks * 32 + q * 8;
        bf16x8 a0 = __builtin_bit_cast(bf16x8, *(const s16x8*)(ldsA + (rowA0 + c) * 128 + ko));
        bf16x8 a1 = __builtin_bit_cast(bf16x8, *(const s16x8*)(ldsA + (rowA0 + 16 + c) * 128 + ko));
#pragma unroll
        for (int n = 0; n < 8; n++) {
            bf16x8 b = __builtin_bit_cast(bf16x8, *(const s16x8*)(ldsW + (n * 16 + c) * 128 + ko));
            acc[0][n] = MFMA(a0, b, acc[0][n]);
            acc[1][n] = MFMA(a1, b, acc[1][n]);
        }
    }
#pragma unroll
    for (int n = 0; n < 8; n++) {
        float bias = b2[n * 16 + c];
#pragma unroll
        for (int t = 0; t < 2; t++)
#pragma unroll
            for (int i = 0; i < 4; i++) {
                int row = m0 + rowA0 + t * 16 + q * 4 + i;
                if (row < N) msg[(size_t)row * 128 + n * 16 + c] = f2bf(acc[t][n][i] + bias);
            }
    }
}

// ---------------------------------------------------------------------------
// CSR build: histogram -> slab starts (unordered) -> fill
// ---------------------------------------------------------------------------
__global__ __launch_bounds__(256) void count_kernel(
    const int* __restrict__ ra, const int* __restrict__ rb,
    int* __restrict__ counts, int E)
{
    int e = blockIdx.x * 256 + threadIdx.x;
    if (e < E) {
        atomicAdd(&counts[rb[e]], 1);
        atomicAdd(&counts[ra[e]], 1);
    }
}

__global__ __launch_bounds__(256) void starts_kernel(
    const int* __restrict__ counts, int* __restrict__ starts,
    int* __restrict__ cur, int* __restrict__ cursor, int N)
{
    int i = blockIdx.x * 256 + threadIdx.x;
    int lane = threadIdx.x & 63;
    int c = (i < N) ? counts[i] : 0;
    int v = c;
#pragma unroll
    for (int d = 1; d < 64; d <<= 1) {
        int t = __shfl_up(v, d);
        if (lane >= d) v += t;
    }
    int total = __shfl(v, 63);
    int base = 0;
    if (lane == 0) base = atomicAdd(cursor, total);
    base = __shfl(base, 0);
    if (i < N) {
        int s = base + v - c;
        starts[i] = s;
        cur[i] = s;
    }
}

__global__ __launch_bounds__(256) void fill_kernel(
    const int* __restrict__ ra, const int* __restrict__ rb,
    int* __restrict__ cur, int* __restrict__ nbr, int E)
{
    int e = blockIdx.x * 256 + threadIdx.x;
    if (e < E) {
        int a = ra[e], b = rb[e];
        int p = atomicAdd(&cur[b], 1); nbr[p] = a;
        int q = atomicAdd(&cur[a], 1); nbr[q] = b;
    }
}

// ---------------------------------------------------------------------------
// Kernel 2: gather — one wave per node, agg[i] = sum_{j in adj(i)} msg[j].
// 16 lanes per row (dwordx4/lane): one load instruction covers 4 neighbor
// rows; unroll x2 => 8 rows in flight per wave. Shuffle-reduce across the
// 4 lane-groups, lanes 0-15 store the bf16 row (16B each = 256B).
// ---------------------------------------------------------------------------
__global__ __launch_bounds__(256) void gather_kernel(
    const short* __restrict__ msg, const int* __restrict__ starts,
    const int* __restrict__ counts, const int* __restrict__ nbr,
    short* __restrict__ aggb, int N)
{
    const int lane = threadIdx.x & 63;
    const int node = blockIdx.x * 4 + (threadIdx.x >> 6);
    if (node >= N) return;
    const int g  = lane >> 4;        // neighbor sub-slot 0..3
    const int cl = lane & 15;        // column chunk: cols cl*8 .. cl*8+7
    const int s = starts[node], end = s + counts[node];

    float a[8];
#pragma unroll
    for (int t = 0; t < 8; t++) a[t] = 0.0f;

    int i = s + g;
    // unrolled x2: 8 rows in flight per wave
    for (; i + 4 < end; i += 8) {
        int j0 = nbr[i];
        int j1 = nbr[i + 4];
        s16x8 p0 = *(const s16x8*)(msg + (size_t)j0 * 128 + cl * 8);
        s16x8 p1 = *(const s16x8*)(msg + (size_t)j1 * 128 + cl * 8);
#pragma unroll
        for (int t = 0; t < 8; t++) a[t] += bf2f(p0[t]);
#pragma unroll
        for (int t = 0; t < 8; t++) a[t] += bf2f(p1[t]);
    }
    if (i < end) {
        int j = nbr[i];
        s16x8 p = *(const s16x8*)(msg + (size_t)j * 128 + cl * 8);
#pragma unroll
        for (int t = 0; t < 8; t++) a[t] += bf2f(p[t]);
    }

    // reduce across the 4 lane-groups (lanes l, l+16, l+32, l+48)
#pragma unroll
    for (int t = 0; t < 8; t++) {
        a[t] += __shfl_xor(a[t], 32);
        a[t] += __shfl_xor(a[t], 16);
    }
    if (g == 0) {
        s16x8 o;
#pragma unroll
        for (int t = 0; t < 8; t++) o[t] = f2bf(a[t]);
        *(s16x8*)(aggb + (size_t)node * 128 + cl * 8) = o;
    }
}

// ---------------------------------------------------------------------------
// Kernel 3: fused GRU (agg bf16).
// ---------------------------------------------------------------------------
__global__ __launch_bounds__(256) void gru_kernel(
    const short* __restrict__ aggb, const float* __restrict__ X,
    const short* __restrict__ GKt, const short* __restrict__ GRt,
    const float* __restrict__ gbias, float* __restrict__ out, int N)
{
    __shared__ short ldsA[128 * 128];   // agg tile (bf16)
    __shared__ short ldsX[128 * 128];   // X tile (bf16)
    const int tid  = threadIdx.x;
    const int m0   = blockIdx.x * 128;
    const int lane = tid & 63, wv = tid >> 6;
    const int q = lane >> 4, c = lane & 15;

    for (int i = tid; i < 128 * 16; i += 256) {
        int r = i >> 4, ch = (i & 15) * 8;
        s16x8 vx, va;
        if (m0 + r < N) {
            vx = cvt8(X + (size_t)(m0 + r) * 128 + ch);
            va = *(const s16x8*)(aggb + (size_t)(m0 + r) * 128 + ch);
        } else { vx = (s16x8)0; va = (s16x8)0; }
        *(s16x8*)(ldsX + r * 128 + ch) = vx;
        *(s16x8*)(ldsA + r * 128 + ch) = va;
    }
    __syncthreads();

#pragma clang loop unroll(disable)
    for (int nn = 0; nn < 2; nn++) {
        const int nt   = wv + nn * 4;
        const int ncol = nt * 16 + c;

        bf16x8 bkz[4], bkr[4], bkh[4], brz[4], brr[4], brh[4];
#pragma unroll
        for (int ks = 0; ks < 4; ks++) {
            int ko = ks * 32 + q * 8;
            bkz[ks] = __builtin_bit_cast(bf16x8, *(const s16x8*)(GKt + (size_t)(ncol)       * 128 + ko));
            bkr[ks] = __builtin_bit_cast(bf16x8, *(const s16x8*)(GKt + (size_t)(128 + ncol) * 128 + ko));
            bkh[ks] = __builtin_bit_cast(bf16x8, *(const s16x8*)(GKt + (size_t)(256 + ncol) * 128 + ko));
            brz[ks] = __builtin_bit_cast(bf16x8, *(const s16x8*)(GRt + (size_t)(ncol)       * 128 + ko));
            brr[ks] = __builtin_bit_cast(bf16x8, *(const s16x8*)(GRt + (size_t)(128 + ncol) * 128 + ko));
            brh[ks] = __builtin_bit_cast(bf16x8, *(const s16x8*)(GRt + (size_t)(256 + ncol) * 128 + ko));
        }
        float bz0 = gbias[ncol],       br0 = gbias[128 + ncol],       bh0 = gbias[256 + ncol];
        float bz1 = gbias[384 + ncol], br1 = gbias[384 + 128 + ncol], bh1 = gbias[384 + 256 + ncol];

#pragma clang loop unroll(disable)
        for (int rt = 0; rt < 8; rt++) {
            f32x4 axz = (f32x4)0.0f, axr = (f32x4)0.0f, axh = (f32x4)0.0f;
            f32x4 arz = (f32x4)0.0f, arr = (f32x4)0.0f, arh = (f32x4)0.0f;
#pragma unroll
            for (int ks = 0; ks < 4; ks++) {
                int ko = ks * 32 + q * 8;
                bf16x8 aA = __builtin_bit_cast(bf16x8, *(const s16x8*)(ldsA + (rt * 16 + c) * 128 + ko));
                bf16x8 aX = __builtin_bit_cast(bf16x8, *(const s16x8*)(ldsX + (rt * 16 + c) * 128 + ko));
                axz = MFMA(aA, bkz[ks], axz);
                axr = MFMA(aA, bkr[ks], axr);
                axh = MFMA(aA, bkh[ks], axh);
                arz = MFMA(aX, brz[ks], arz);
                arr = MFMA(aX, brr[ks], arr);
                arh = MFMA(aX, brh[ks], arh);
            }
#pragma unroll
            for (int i = 0; i < 4; i++) {
                int row  = rt * 16 + q * 4 + i;
                int grow = m0 + row;
                if (grow < N) {
                    float z  = sigmoid_(axz[i] + bz0 + arz[i] + bz1);
                    float r  = sigmoid_(axr[i] + br0 + arr[i] + br1);
                    float hh = tanh_(axh[i] + bh0 + r * (arh[i] + bh1));
                    float xv = X[(size_t)grow * 128 + ncol];   // fp32 for exact blend
                    out[(size_t)grow * 128 + ncol] = z * xv + (1.0f - z) * hh;
                }
            }
        }
    }
}

// ---------------------------------------------------------------------------
extern "C" void kernel_launch(void* const* d_in, const int* in_sizes, int n_in,
                              void* d_out, int out_size, void* d_ws, size_t ws_size,
                              hipStream_t stream)
{
    const float* X  = (const float*)d_in[0];
    const int*   ra = (const int*)d_in[1];
    const int*   rb = (const int*)d_in[2];
    const float* W1 = (const float*)d_in[3];
    const float* b1 = (const float*)d_in[4];
    const float* W2 = (const float*)d_in[5];
    const float* b2 = (const float*)d_in[6];
    const float* GK = (const float*)d_in[7];
    const float* GR = (const float*)d_in[8];
    const float* GB = (const float*)d_in[9];
    const int N = in_sizes[0] / 128;
    const int E = in_sizes[1];
    float* out = (float*)d_out;

    char* ws = (char*)d_ws;
    size_t off = 0;
    short* aggb = (short*)(ws + off); off += (size_t)N * 128 * 2;   // bf16 agg
    short* msg  = (short*)(ws + off); off += (size_t)N * 128 * 2;
    short* W1t  = (short*)(ws + off); off += 16384u * 2;
    short* W2t  = (short*)(ws + off); off += 16384u * 2;
    short* GKt  = (short*)(ws + off); off += 49152u * 2;
    short* GRt  = (short*)(ws + off); off += 49152u * 2;
    int* counts = (int*)(ws + off);   off += (size_t)N * 4;
    int* cursor = (int*)(ws + off);   off += 4;
    int* starts = (int*)(ws + off);   off += (size_t)N * 4;
    int* cur    = (int*)(ws + off);   off += (size_t)N * 4;
    int* nbr    = (int*)(ws + off);   off += (size_t)2 * E * 4;

    const int pblk = ((N > 49152 ? N : 49152) + 255) / 256;
    prep_kernel<<<pblk, 256, 0, stream>>>(W1, W2, GK, GR, W1t, W2t, GKt, GRt,
                                          counts, cursor, N);

    const int eblk = (E + 255) / 256;
    count_kernel<<<eblk, 256, 0, stream>>>(ra, rb, counts, E);
    starts_kernel<<<(N + 255) / 256, 256, 0, stream>>>(counts, starts, cur, cursor, N);
    fill_kernel<<<eblk, 256, 0, stream>>>(ra, rb, cur, nbr, E);

    const int nblk = (N + 127) / 128;
    msg_kernel<<<nblk, 256, 0, stream>>>(X, W1t, b1, W2t, b2, msg, N);
    gather_kernel<<<(N + 3) / 4, 256, 0, stream>>>(msg, starts, counts, nbr, aggb, N);
    gru_kernel<<<nblk, 256, 0, stream>>>(aggb, X, GKt, GRt, GB, out, N);
}